// Round 1
// baseline (7009.078 us; speedup 1.0000x reference)
//
#include <hip/hip_runtime.h>
#include <math.h>

#define BATCH 4096
#define TT 48
#define DDIM 59
#define HHID 256
#define RR 16            // batch rows per workgroup
#define NWG (BATCH/RR)   // 256 workgroups

// ---- output layout (floats) ----
static constexpr size_t N_XIMP  = (size_t)BATCH*TT*DDIM;   // 11,599,872
static constexpr size_t OFF_LOSS = N_XIMP;
static constexpr size_t OFF_HS   = OFF_LOSS + 1;
static constexpr size_t N_HS     = (size_t)BATCH*TT*HHID;  // 50,331,648
static constexpr size_t OFF_YOUT = OFF_HS + N_HS;
static constexpr size_t OFF_YSC  = OFF_YOUT + BATCH;
static constexpr size_t OFF_DEC  = OFF_YSC + BATCH;

__device__ __forceinline__ float sigm(float v){ return 1.f/(1.f+expf(-v)); }

// =====================================================================
// decay_factor: fully parallel over B*T rows.
// decay[b,t,e] = 0.5*(1 - tanh(sign(dd[e]) * |dd @ wobs_W.T + wobs_b|[e]))
// =====================================================================
__global__ __launch_bounds__(256) void decay_kernel(
    const float* __restrict__ deltas, const float* __restrict__ medians,
    const float* __restrict__ wobs_W, const float* __restrict__ wobs_b,
    float* __restrict__ out_decay)
{
  __shared__ float sW[DDIM][60];
  __shared__ float sb[64], smed[64];
  __shared__ float sdd[16][60];
  const int tid = threadIdx.x;
  for (int idx = tid; idx < DDIM*DDIM; idx += 256){
    int e = idx/DDIM, d = idx - e*DDIM;
    sW[e][d] = wobs_W[idx];
  }
  if (tid < DDIM){ sb[tid] = wobs_b[tid]; smed[tid] = medians[tid]; }
  __syncthreads();
  const size_t row0 = (size_t)blockIdx.x * 16;   // rows over B*T
  for (int idx = tid; idx < 16*DDIM; idx += 256){
    int r = idx/DDIM, d = idx - r*DDIM;
    sdd[r][d] = deltas[(row0+r)*DDIM + d] - smed[d];
  }
  __syncthreads();
  for (int idx = tid; idx < 16*DDIM; idx += 256){
    int r = idx/DDIM, e = idx - r*DDIM;
    float acc = sb[e];
    for (int d = 0; d < DDIM; d++) acc += sdd[r][d]*sW[e][d];
    float dd = sdd[r][e];
    float sg = (dd > 0.f) ? 1.f : ((dd < 0.f) ? -1.f : 0.f);
    out_decay[(row0+r)*DDIM + e] = 0.5f*(1.f - tanhf(sg*fabsf(acc)));
  }
}

// =====================================================================
// Sequential scan: one WG handles RR=16 batch rows through all T steps.
// h kept in LDS. Phases per step:
//  P1 gamma_h + h*=gamma  | P2 x_h = h@hist_W.T | P3 feat/beta/x_comb/
//  x_imp/loss             | P4 GRU (gi+gh+gates)
// =====================================================================
__global__ __launch_bounds__(256, 1) void seq_kernel(
    const float* __restrict__ x, const float* __restrict__ mask,
    const float* __restrict__ deltas, const float* __restrict__ h0,
    const float* __restrict__ W_dh, const float* __restrict__ b_dh,
    const float* __restrict__ W_dx, const float* __restrict__ b_dx,
    const float* __restrict__ hist_W, const float* __restrict__ hist_b,
    const float* __restrict__ feat_W, const float* __restrict__ feat_b,
    const float* __restrict__ wcomb_W, const float* __restrict__ wcomb_b,
    const float* __restrict__ W_ih, const float* __restrict__ W_hh,
    const float* __restrict__ b_ih, const float* __restrict__ b_hh,
    float* __restrict__ out_ximp, float* __restrict__ out_hs,
    float* __restrict__ ws_num, float* __restrict__ ws_den)
{
  __shared__ float sh[RR][HHID+4];     // 16 x 260 (float4-aligned rows)
  __shared__ float sdT[DDIM][16];      // transposed deltas tile
  __shared__ float sx[RR][60], smk[RR][60], sd[RR][60];
  __shared__ float sxh[RR][60], sxr[RR][60], sgx[RR][60];
  __shared__ float scat[RR][120];      // [x_imp | m] concat for GRU input
  __shared__ float sdiag[64], sbdx[64];
  __shared__ float sredN[4], sredD[4];

  const int tid  = threadIdx.x;
  const int lane = tid & 63;
  const int wid  = tid >> 6;
  const int row0 = blockIdx.x * RR;

  if (tid < DDIM){ sdiag[tid] = W_dx[tid*DDIM + tid]; sbdx[tid] = b_dx[tid]; }
  #pragma unroll
  for (int r = 0; r < RR; r++) sh[r][tid] = h0[(size_t)(row0+r)*HHID + tid];

  // hoisted per-thread constants (thread tid owns h-column tid and gate rows tid, tid+256, tid+512)
  const float bdh  = b_dh[tid];
  const float bihr = b_ih[tid]        + b_hh[tid];
  const float bihz = b_ih[HHID+tid]   + b_hh[HHID+tid];
  const float bin_ = b_ih[2*HHID+tid];
  const float bhn_ = b_hh[2*HHID+tid];
  const float* wdh_row = W_dh + (size_t)tid*DDIM;
  const float* wi0 = W_ih + (size_t)tid*118;
  const float* wi1 = W_ih + (size_t)(HHID+tid)*118;
  const float* wi2 = W_ih + (size_t)(2*HHID+tid)*118;
  const float* wh0 = W_hh + (size_t)tid*HHID;
  const float* wh1 = W_hh + (size_t)(HHID+tid)*HHID;
  const float* wh2 = W_hh + (size_t)(2*HHID+tid)*HHID;

  __syncthreads();

  for (int t = 0; t < TT; t++){
    // ---- stage x, m, d tiles ----
    for (int idx = tid; idx < RR*DDIM; idx += 256){
      int r = idx/DDIM, d = idx - r*DDIM;
      size_t g = ((size_t)(row0+r)*TT + t)*DDIM + d;
      float xv = x[g], mv = mask[g], dv = deltas[g];
      sx[r][d] = xv; smk[r][d] = mv; sd[r][d] = dv;
      sdT[d][r] = dv;
      scat[r][DDIM+d] = mv;      // m-half of GRU input concat
    }
    __syncthreads();

    // ---- P1: gamma_h = exp(-relu(d @ W_dh.T + b_dh)); h *= gamma ----
    {
      float acc[RR];
      #pragma unroll
      for (int r = 0; r < RR; r++) acc[r] = bdh;
      for (int d = 0; d < DDIM; d++){
        float w = wdh_row[d];
        const float4* dp = reinterpret_cast<const float4*>(&sdT[d][0]);
        float4 v0 = dp[0], v1 = dp[1], v2 = dp[2], v3 = dp[3];
        acc[0] += v0.x*w; acc[1] += v0.y*w; acc[2]  += v0.z*w; acc[3]  += v0.w*w;
        acc[4] += v1.x*w; acc[5] += v1.y*w; acc[6]  += v1.z*w; acc[7]  += v1.w*w;
        acc[8] += v2.x*w; acc[9] += v2.y*w; acc[10] += v2.z*w; acc[11] += v2.w*w;
        acc[12]+= v3.x*w; acc[13]+= v3.y*w; acc[14] += v3.z*w; acc[15] += v3.w*w;
      }
      #pragma unroll
      for (int r = 0; r < RR; r++){
        float g = expf(-fmaxf(acc[r], 0.f));
        sh[r][tid] *= g;
      }
    }
    __syncthreads();

    // ---- P2: x_h = h @ hist_W.T + hist_b  (thread = (dcol, quarter)) ----
    {
      int dcol = tid >> 2, q = tid & 3;
      float accr[RR];
      #pragma unroll
      for (int r = 0; r < RR; r++) accr[r] = 0.f;
      if (dcol < DDIM){
        const float* wp = hist_W + (size_t)dcol*HHID + q*64;
        for (int jj = 0; jj < 64; jj += 4){
          float4 w = *reinterpret_cast<const float4*>(wp + jj);
          #pragma unroll
          for (int r = 0; r < RR; r++){
            float4 hv = *reinterpret_cast<const float4*>(&sh[r][q*64 + jj]);
            accr[r] += hv.x*w.x + hv.y*w.y + hv.z*w.z + hv.w*w.w;
          }
        }
      }
      #pragma unroll
      for (int r = 0; r < RR; r++){
        float v = accr[r];
        v += __shfl_xor(v, 1);
        v += __shfl_xor(v, 2);
        if (q == 0 && dcol < DDIM) sxh[r][dcol] = v + hist_b[dcol];
      }
    }
    __syncthreads();

    // ---- P3a: x_r, gamma_x ----
    for (int idx = tid; idx < RR*DDIM; idx += 256){
      int r = idx/DDIM, d = idx - r*DDIM;
      float m  = smk[r][d];
      float xh = sxh[r][d];
      sxr[r][d] = m*sx[r][d] + (1.f-m)*xh;
      sgx[r][d] = expf(-fmaxf(sd[r][d]*sdiag[d] + sbdx[d], 0.f));
    }
    __syncthreads();

    // ---- P3b: xu, beta, x_comb, x_imp, loss ----
    float lnum = 0.f, lden = 0.f;
    for (int idx = tid; idx < RR*DDIM; idx += 256){
      int r = idx/DDIM, i = idx - r*DDIM;
      const float* fr = feat_W + (size_t)i*DDIM;
      float u = feat_b[i];
      for (int d = 0; d < DDIM; d++) u += sxr[r][d]*fr[d];
      u -= sxr[r][i]*fr[i];                       // zero the diagonal
      const float* wc = wcomb_W + (size_t)i*118;
      float bacc = wcomb_b[i];
      for (int d = 0; d < DDIM; d++) bacc += sgx[r][d]*wc[d];
      for (int d = 0; d < DDIM; d++) bacc += smk[r][d]*wc[DDIM+d];
      float bta = sigm(bacc);
      float xh = sxh[r][i];
      float xc = bta*u + (1.f-bta)*xh;
      float m = smk[r][i], xv = sx[r][i];
      lnum += fabsf(xv - xc)*m;
      lden += m;
      float xi = m*xv + (1.f-m)*xc;
      scat[r][i] = xi;
      out_ximp[((size_t)(row0+r)*TT + t)*DDIM + i] = xi;
    }
    #pragma unroll
    for (int off = 32; off >= 1; off >>= 1){
      lnum += __shfl_xor(lnum, off);
      lden += __shfl_xor(lden, off);
    }
    if (lane == 0){ sredN[wid] = lnum; sredD[wid] = lden; }
    __syncthreads();
    if (tid == 0){
      atomicAdd(&ws_num[t], sredN[0]+sredN[1]+sredN[2]+sredN[3]);
      atomicAdd(&ws_den[t], sredD[0]+sredD[1]+sredD[2]+sredD[3]);
    }

    // ---- P4: GRU — gi = [x_imp|m]@W_ih.T, gh = h@W_hh.T, gates ----
    {
      float a0[RR], a1[RR], ani[RR], anh[RR];
      #pragma unroll
      for (int r = 0; r < RR; r++){ a0[r]=bihr; a1[r]=bihz; ani[r]=bin_; anh[r]=bhn_; }
      for (int c = 0; c < 118; c += 2){
        float2 w0 = *reinterpret_cast<const float2*>(wi0 + c);
        float2 w1 = *reinterpret_cast<const float2*>(wi1 + c);
        float2 w2 = *reinterpret_cast<const float2*>(wi2 + c);
        #pragma unroll
        for (int r = 0; r < RR; r++){
          float2 v = *reinterpret_cast<const float2*>(&scat[r][c]);
          a0[r]  += v.x*w0.x + v.y*w0.y;
          a1[r]  += v.x*w1.x + v.y*w1.y;
          ani[r] += v.x*w2.x + v.y*w2.y;
        }
      }
      for (int j = 0; j < HHID; j += 4){
        float4 w0 = *reinterpret_cast<const float4*>(wh0 + j);
        float4 w1 = *reinterpret_cast<const float4*>(wh1 + j);
        float4 w2 = *reinterpret_cast<const float4*>(wh2 + j);
        #pragma unroll
        for (int r = 0; r < RR; r++){
          float4 hv = *reinterpret_cast<const float4*>(&sh[r][j]);
          a0[r]  += hv.x*w0.x + hv.y*w0.y + hv.z*w0.z + hv.w*w0.w;
          a1[r]  += hv.x*w1.x + hv.y*w1.y + hv.z*w1.z + hv.w*w1.w;
          anh[r] += hv.x*w2.x + hv.y*w2.y + hv.z*w2.z + hv.w*w2.w;
        }
      }
      float hnew[RR];
      #pragma unroll
      for (int r = 0; r < RR; r++){
        float rg = sigm(a0[r]);
        float zg = sigm(a1[r]);
        float ng = tanhf(ani[r] + rg*anh[r]);
        hnew[r] = (1.f-zg)*ng + zg*sh[r][tid];
      }
      __syncthreads();   // all P4 reads of sh/scat done before overwrite
      #pragma unroll
      for (int r = 0; r < RR; r++){
        sh[r][tid] = hnew[r];
        out_hs[((size_t)(row0+r)*TT + t)*HHID + tid] = hnew[r];
      }
    }
    __syncthreads();
  }
}

// =====================================================================
// finalize: x_loss = sum_t num/den ; y_out = h_last @ cls_W.T + cls_b
// =====================================================================
__global__ __launch_bounds__(256) void final_kernel(
    const float* __restrict__ hs, const float* __restrict__ cls_W,
    const float* __restrict__ cls_b, const float* __restrict__ ws_num,
    const float* __restrict__ ws_den, float* __restrict__ out)
{
  int b = blockIdx.x*256 + threadIdx.x;
  if (b < BATCH){
    const float* hr = hs + ((size_t)b*TT + (TT-1))*HHID;
    float acc = cls_b[0];
    for (int j = 0; j < HHID; j++) acc += hr[j]*cls_W[j];
    out[OFF_YOUT + b] = acc;
    out[OFF_YSC  + b] = sigm(acc);
  }
  if (blockIdx.x == 0 && threadIdx.x == 0){
    float s = 0.f;
    for (int tt = 0; tt < TT; tt++) s += ws_num[tt]/(ws_den[tt] + 1e-5f);
    out[OFF_LOSS] = s;
  }
}

extern "C" void kernel_launch(void* const* d_in, const int* in_sizes, int n_in,
                              void* d_out, int out_size, void* d_ws, size_t ws_size,
                              hipStream_t stream)
{
  const float* x       = (const float*)d_in[0];
  const float* mask_   = (const float*)d_in[1];
  const float* deltas  = (const float*)d_in[2];
  // d_in[3] = last_obs (unused by reference)
  const float* h0      = (const float*)d_in[4];
  const float* medians = (const float*)d_in[5];
  const float* W_dh    = (const float*)d_in[6];
  const float* b_dh    = (const float*)d_in[7];
  const float* W_dx    = (const float*)d_in[8];
  const float* b_dx    = (const float*)d_in[9];
  const float* hist_W  = (const float*)d_in[10];
  const float* hist_b  = (const float*)d_in[11];
  const float* feat_W  = (const float*)d_in[12];
  const float* feat_b  = (const float*)d_in[13];
  const float* wcomb_W = (const float*)d_in[14];
  const float* wcomb_b = (const float*)d_in[15];
  const float* wobs_W  = (const float*)d_in[16];
  const float* wobs_b  = (const float*)d_in[17];
  const float* W_ih    = (const float*)d_in[18];
  const float* W_hh    = (const float*)d_in[19];
  const float* b_ih    = (const float*)d_in[20];
  const float* b_hh    = (const float*)d_in[21];
  const float* cls_W   = (const float*)d_in[22];
  const float* cls_b   = (const float*)d_in[23];

  float* out    = (float*)d_out;
  float* ws_num = (float*)d_ws;
  float* ws_den = ws_num + TT;

  hipMemsetAsync(d_ws, 0, 2*TT*sizeof(float), stream);

  decay_kernel<<<BATCH*TT/16, 256, 0, stream>>>(deltas, medians, wobs_W, wobs_b,
                                                out + OFF_DEC);

  seq_kernel<<<NWG, 256, 0, stream>>>(x, mask_, deltas, h0, W_dh, b_dh, W_dx, b_dx,
      hist_W, hist_b, feat_W, feat_b, wcomb_W, wcomb_b, W_ih, W_hh, b_ih, b_hh,
      out /*x_imp*/, out + OFF_HS, ws_num, ws_den);

  final_kernel<<<BATCH/256, 256, 0, stream>>>(out + OFF_HS, cls_W, cls_b,
                                              ws_num, ws_den, out);
}

// Round 2
// 1426.480 us; speedup vs baseline: 4.9135x; 4.9135x over previous
//
#include <hip/hip_runtime.h>
#include <math.h>

#define BATCH 4096
#define TT 48
#define DDIM 59
#define HHID 256
#define RR 16
#define NWG (BATCH/RR)     // 256 workgroups
#define NTHR 512           // 8 waves

typedef _Float16 f16;
typedef _Float16 f16x8 __attribute__((ext_vector_type(8)));
typedef float    f32x4 __attribute__((ext_vector_type(4)));

// ---- output layout (floats) ----
static constexpr size_t N_XIMP   = (size_t)BATCH*TT*DDIM;
static constexpr size_t OFF_LOSS = N_XIMP;
static constexpr size_t OFF_HS   = OFF_LOSS + 1;
static constexpr size_t N_HS     = (size_t)BATCH*TT*HHID;
static constexpr size_t OFF_YOUT = OFF_HS + N_HS;
static constexpr size_t OFF_YSC  = OFF_YOUT + BATCH;
static constexpr size_t OFF_DEC  = OFF_YSC + BATCH;

// ---- f16 weight workspace layout (element offsets from wbase) ----
// blocks of [64 lanes][8 e] f16 = 512 f16 = 1KB each
static constexpr size_t WOFF_GRU  = 0;          // 16 jb * 36 blocks
static constexpr size_t WOFF_DH   = 294912;     // 16 nt * 2 kt
static constexpr size_t WOFF_HIST = 311296;     // 4 nt * 8 kt
static constexpr size_t WOFF_FEAT = 327680;     // 4 nt * 2 kt
static constexpr size_t WOFF_WC   = 331776;     // 4 nt * 4 kt
// total 339968 f16 = 679936 B (+512 B loss prefix) in d_ws

__device__ __forceinline__ float sigm(float v){ return 1.f/(1.f+expf(-v)); }

// =====================================================================
// decay_factor (fully parallel, unchanged from round 1)
// =====================================================================
__global__ __launch_bounds__(256) void decay_kernel(
    const float* __restrict__ deltas, const float* __restrict__ medians,
    const float* __restrict__ wobs_W, const float* __restrict__ wobs_b,
    float* __restrict__ out_decay)
{
  __shared__ float sW[DDIM][60];
  __shared__ float sb[64], smed[64];
  __shared__ float sdd[16][60];
  const int tid = threadIdx.x;
  for (int idx = tid; idx < DDIM*DDIM; idx += 256){
    int e = idx/DDIM, d = idx - e*DDIM;
    sW[e][d] = wobs_W[idx];
  }
  if (tid < DDIM){ sb[tid] = wobs_b[tid]; smed[tid] = medians[tid]; }
  __syncthreads();
  const size_t row0 = (size_t)blockIdx.x * 16;
  for (int idx = tid; idx < 16*DDIM; idx += 256){
    int r = idx/DDIM, d = idx - r*DDIM;
    sdd[r][d] = deltas[(row0+r)*DDIM + d] - smed[d];
  }
  __syncthreads();
  for (int idx = tid; idx < 16*DDIM; idx += 256){
    int r = idx/DDIM, e = idx - r*DDIM;
    float acc = sb[e];
    for (int d = 0; d < DDIM; d++) acc += sdd[r][d]*sW[e][d];
    float dd = sdd[r][e];
    float sg = (dd > 0.f) ? 1.f : ((dd < 0.f) ? -1.f : 0.f);
    out_decay[(row0+r)*DDIM + e] = 0.5f*(1.f - tanhf(sg*fabsf(acc)));
  }
}

// =====================================================================
// Weight conversion: fp32 -> f16 MFMA B-fragment blocks.
// B-frag layout (16x16x32): lane l holds B[k = kt*32+(l>>4)*8+e][n = nt*16+(l&15)]
// stored contiguously: block*512 + l*8 + e.
// GRU per jb (0..15): [r kt0..11][z kt0..11][nh kt0..7][ni kt0..3]
//   r/z: row g*256+jb*16+nl; k<256 -> W_hh, 256..373 -> W_ih[k-256], else 0
//   nh : row 512+jb*16+nl; W_hh[k]
//   ni : row 512+jb*16+nl; k'<118 -> W_ih[k'] else 0   (A ktiles 8..11)
// =====================================================================
__global__ __launch_bounds__(256) void conv_kernel(
    const float* __restrict__ W_dh, const float* __restrict__ hist_W,
    const float* __restrict__ feat_W, const float* __restrict__ wcomb_W,
    const float* __restrict__ W_ih, const float* __restrict__ W_hh,
    f16* __restrict__ ws)
{
  const int g  = blockIdx.x*4 + (threadIdx.x >> 6);
  const int l  = threadIdx.x & 63;
  const int nl = l & 15;
  const int kh = (l >> 4) * 8;
  f16x8 out;
  if (g < 576){                                   // GRU
    int jb = g/36, s = g - jb*36;
    if (s < 24){                                  // r or z (fused ih+hh)
      int gate = s/12, kt = s - gate*12;
      int row  = gate*256 + jb*16 + nl;
      #pragma unroll
      for (int e = 0; e < 8; e++){
        int k = kt*32 + kh + e;
        float v = (k < 256) ? W_hh[(size_t)row*256 + k]
                : (k < 374) ? W_ih[(size_t)row*118 + (k-256)] : 0.f;
        out[e] = (f16)v;
      }
    } else if (s < 32){                           // n-gate hidden part
      int kt = s - 24, row = 512 + jb*16 + nl;
      #pragma unroll
      for (int e = 0; e < 8; e++){
        int k = kt*32 + kh + e;
        out[e] = (f16)W_hh[(size_t)row*256 + k];
      }
    } else {                                      // n-gate input part
      int kt = s - 32, row = 512 + jb*16 + nl;
      #pragma unroll
      for (int e = 0; e < 8; e++){
        int k = kt*32 + kh + e;                   // 0..127 over [x|m]
        out[e] = (f16)((k < 118) ? W_ih[(size_t)row*118 + k] : 0.f);
      }
    }
    *(f16x8*)&ws[WOFF_GRU + (size_t)g*512 + l*8] = out;
  } else if (g < 608){                            // gamma_h decay W_dh
    int i = g - 576, nt = i >> 1, kt = i & 1;
    int row = nt*16 + nl;
    #pragma unroll
    for (int e = 0; e < 8; e++){
      int k = kt*32 + kh + e;
      out[e] = (f16)((k < 59) ? W_dh[(size_t)row*59 + k] : 0.f);
    }
    *(f16x8*)&ws[WOFF_DH + (size_t)i*512 + l*8] = out;
  } else if (g < 640){                            // hist_W
    int i = g - 608, nt = i >> 3, kt = i & 7;
    int n = nt*16 + nl;
    #pragma unroll
    for (int e = 0; e < 8; e++){
      int k = kt*32 + kh + e;
      out[e] = (f16)((n < 59) ? hist_W[(size_t)n*256 + k] : 0.f);
    }
    *(f16x8*)&ws[WOFF_HIST + (size_t)i*512 + l*8] = out;
  } else if (g < 648){                            // feat_W (off-diag mask baked in)
    int i = g - 640, nt = i >> 1, kt = i & 1;
    int n = nt*16 + nl;
    #pragma unroll
    for (int e = 0; e < 8; e++){
      int k = kt*32 + kh + e;
      out[e] = (f16)((n < 59 && k < 59 && k != n) ? feat_W[(size_t)n*59 + k] : 0.f);
    }
    *(f16x8*)&ws[WOFF_FEAT + (size_t)i*512 + l*8] = out;
  } else {                                        // wcomb_W
    int i = g - 648, nt = i >> 2, kt = i & 3;
    int n = nt*16 + nl;
    #pragma unroll
    for (int e = 0; e < 8; e++){
      int k = kt*32 + kh + e;
      out[e] = (f16)((n < 59 && k < 118) ? wcomb_W[(size_t)n*118 + k] : 0.f);
    }
    *(f16x8*)&ws[WOFF_WC + (size_t)i*512 + l*8] = out;
  }
}

// =====================================================================
// Sequential scan, MFMA edition. One WG = 16 batch rows (one M-tile),
// 512 threads = 8 waves. A-tiles in LDS f16 (padded strides), weights
// streamed as prepacked B-fragments from d_ws (L2-resident).
// A-frag (16x16x32): lane l holds A[m=l&15][k = kt*32+(l>>4)*8+e]
// C/D: lane l, reg q -> row m=(l>>4)*4+q, col n=nt*16+(l&15)
// =====================================================================
__global__ __launch_bounds__(NTHR, 1) void seq_kernel(
    const float* __restrict__ x, const float* __restrict__ mask,
    const float* __restrict__ deltas, const float* __restrict__ h0,
    const float* __restrict__ b_dh, const float* __restrict__ W_dx,
    const float* __restrict__ b_dx, const float* __restrict__ hist_b,
    const float* __restrict__ feat_b, const float* __restrict__ wcomb_b,
    const float* __restrict__ b_ih, const float* __restrict__ b_hh,
    const f16* __restrict__ wb,
    float* __restrict__ out_ximp, float* __restrict__ out_hs,
    float* __restrict__ ws_num, float* __restrict__ ws_den)
{
  // f16 A-tiles; row strides chosen so stride_words % 32 == 4 (2-way max)
  __shared__ f16 Acat[16*392];   // [h(256) | x_imp(59) | m(59) | pad0(10+)]
  __shared__ f16 Ad  [16*72];    // deltas (k<59, pad0)
  __shared__ f16 Axr [16*72];    // x_r
  __shared__ f16 Agm [16*136];   // [gamma_x(59) | m(59) | pad0(10)]
  __shared__ float ssx[16*60], ssm[16*60], ssd[16*60];
  __shared__ float sxh[16*60], sxu[16*60], sbt[16*60];
  __shared__ float sh [16*260];  // fp32 hidden state
  __shared__ float sdiag[64], sbdx[64];
  __shared__ float sredN[8], sredD[8];

  const int tid = threadIdx.x;
  const int w   = tid >> 6;
  const int l   = tid & 63;
  const int nl  = l & 15;
  const int kh  = (l >> 4) * 8;   // k sub-offset of this lane's A/B frag
  const int mq  = (l >> 4) * 4;   // first C/D row of this lane
  const int row0 = blockIdx.x * RR;

  const f16* Bgru  = wb + WOFF_GRU;
  const f16* Bdh   = wb + WOFF_DH;
  const f16* Bhist = wb + WOFF_HIST;
  const f16* Bfeat = wb + WOFF_FEAT;
  const f16* Bwc   = wb + WOFF_WC;

  if (tid < DDIM){ sdiag[tid] = W_dx[(size_t)tid*DDIM + tid]; sbdx[tid] = b_dx[tid]; }
  // zero A-tile pads once (MFMA reads them; B is zero there but avoid NaN*0)
  for (int idx = tid; idx < 16*18; idx += NTHR){
    int r = idx/18, c = idx - (idx/18)*18;
    Acat[r*392 + 374 + c] = (f16)0.f;
    Agm [r*136 + 118 + c] = (f16)0.f;
  }
  for (int idx = tid; idx < 16*13; idx += NTHR){
    int r = idx/13, c = idx - (idx/13)*13;
    Ad [r*72 + 59 + c] = (f16)0.f;
    Axr[r*72 + 59 + c] = (f16)0.f;
  }
  for (int idx = tid; idx < 16*256; idx += NTHR){
    int r = idx >> 8, j = idx & 255;
    sh[r*260 + j] = h0[(size_t)(row0+r)*HHID + j];
  }
  __syncthreads();

  for (int t = 0; t < TT; t++){
    // ---- stage x, m, d ----
    for (int idx = tid; idx < 944; idx += NTHR){
      int r = idx/59, d = idx - r*59;
      size_t g = ((size_t)(row0+r)*TT + t)*DDIM + d;
      float xv = x[g], mv = mask[g], dv = deltas[g];
      ssx[r*60+d] = xv; ssm[r*60+d] = mv; ssd[r*60+d] = dv;
      Ad  [r*72 +d]      = (f16)dv;
      Agm [r*136+59+d]   = (f16)mv;
      Acat[r*392+315+d]  = (f16)mv;
    }
    __syncthreads();

    // ---- gamma_h MFMA: [16x64]@W_dh^T -> h *= exp(-relu(.)) ----
    #pragma unroll
    for (int ii = 0; ii < 2; ii++){
      int nt = 2*w + ii;
      f32x4 acc = {0.f,0.f,0.f,0.f};
      #pragma unroll
      for (int kt = 0; kt < 2; kt++){
        f16x8 a = *(const f16x8*)&Ad[nl*72 + kt*32 + kh];
        f16x8 b = *(const f16x8*)&Bdh[(size_t)(nt*2+kt)*512 + l*8];
        acc = __builtin_amdgcn_mfma_f32_16x16x32_f16(a, b, acc, 0, 0, 0);
      }
      int n = nt*16 + nl;
      float bn = b_dh[n];
      #pragma unroll
      for (int q = 0; q < 4; q++){
        int m = mq + q;
        float gm = expf(-fmaxf(acc[q] + bn, 0.f));
        float hv = sh[m*260 + n] * gm;
        sh[m*260 + n] = hv;
        Acat[m*392 + n] = (f16)hv;
      }
    }
    __syncthreads();

    // ---- x_h MFMA (waves 0-3) || gamma_x VALU (waves 4-7) ----
    if (w < 4){
      int nt = w;
      f32x4 acc = {0.f,0.f,0.f,0.f};
      #pragma unroll
      for (int kt = 0; kt < 8; kt++){
        f16x8 a = *(const f16x8*)&Acat[nl*392 + kt*32 + kh];
        f16x8 b = *(const f16x8*)&Bhist[(size_t)(nt*8+kt)*512 + l*8];
        acc = __builtin_amdgcn_mfma_f32_16x16x32_f16(a, b, acc, 0, 0, 0);
      }
      int n = nt*16 + nl;
      if (n < DDIM){
        float hb = hist_b[n];
        #pragma unroll
        for (int q = 0; q < 4; q++) sxh[(mq+q)*60 + n] = acc[q] + hb;
      }
    } else {
      for (int idx = tid - 256; idx < 944; idx += 256){
        int r = idx/59, d = idx - r*59;
        float gx = expf(-fmaxf(ssd[r*60+d]*sdiag[d] + sbdx[d], 0.f));
        Agm[r*136 + d] = (f16)gx;
      }
    }
    __syncthreads();

    // ---- x_r ----
    for (int idx = tid; idx < 944; idx += NTHR){
      int r = idx/59, d = idx - r*59;
      float m = ssm[r*60+d];
      float xr = m*ssx[r*60+d] + (1.f-m)*sxh[r*60+d];
      Axr[r*72+d] = (f16)xr;
    }
    __syncthreads();

    // ---- feat MFMA (waves 0-3) || beta MFMA (waves 4-7) ----
    if (w < 4){
      int nt = w;
      f32x4 acc = {0.f,0.f,0.f,0.f};
      #pragma unroll
      for (int kt = 0; kt < 2; kt++){
        f16x8 a = *(const f16x8*)&Axr[nl*72 + kt*32 + kh];
        f16x8 b = *(const f16x8*)&Bfeat[(size_t)(nt*2+kt)*512 + l*8];
        acc = __builtin_amdgcn_mfma_f32_16x16x32_f16(a, b, acc, 0, 0, 0);
      }
      int n = nt*16 + nl;
      if (n < DDIM){
        float fb = feat_b[n];
        #pragma unroll
        for (int q = 0; q < 4; q++) sxu[(mq+q)*60 + n] = acc[q] + fb;
      }
    } else {
      int nt = w - 4;
      f32x4 acc = {0.f,0.f,0.f,0.f};
      #pragma unroll
      for (int kt = 0; kt < 4; kt++){
        f16x8 a = *(const f16x8*)&Agm[nl*136 + kt*32 + kh];
        f16x8 b = *(const f16x8*)&Bwc[(size_t)(nt*4+kt)*512 + l*8];
        acc = __builtin_amdgcn_mfma_f32_16x16x32_f16(a, b, acc, 0, 0, 0);
      }
      int n = nt*16 + nl;
      if (n < DDIM){
        float cb = wcomb_b[n];
        #pragma unroll
        for (int q = 0; q < 4; q++) sbt[(mq+q)*60 + n] = sigm(acc[q] + cb);
      }
    }
    __syncthreads();

    // ---- x_comb / loss / x_imp ----
    float lnum = 0.f, lden = 0.f;
    for (int idx = tid; idx < 944; idx += NTHR){
      int r = idx/59, i = idx - r*59;
      float xh = sxh[r*60+i], xu = sxu[r*60+i], bt = sbt[r*60+i];
      float xc = bt*xu + (1.f-bt)*xh;
      float m = ssm[r*60+i], xv = ssx[r*60+i];
      lnum += fabsf(xv - xc)*m;
      lden += m;
      float xi = m*xv + (1.f-m)*xc;
      Acat[r*392 + 256 + i] = (f16)xi;
      out_ximp[((size_t)(row0+r)*TT + t)*DDIM + i] = xi;
    }
    #pragma unroll
    for (int off = 32; off >= 1; off >>= 1){
      lnum += __shfl_xor(lnum, off);
      lden += __shfl_xor(lden, off);
    }
    if (l == 0){ sredN[w] = lnum; sredD[w] = lden; }
    __syncthreads();
    if (tid == 0){
      float a = 0.f, b = 0.f;
      #pragma unroll
      for (int k = 0; k < 8; k++){ a += sredN[k]; b += sredD[k]; }
      atomicAdd(&ws_num[t], a); atomicAdd(&ws_den[t], b);
    }

    // ---- GRU MFMA: r,z fused(K=384); nh(K=256); ni(K=128 over ktiles 8-11) ----
    #pragma unroll
    for (int jj = 0; jj < 2; jj++){
      int jb = 2*w + jj;
      const f16* Bb = Bgru + (size_t)jb*36*512;
      f32x4 ar  = {0.f,0.f,0.f,0.f};
      f32x4 az  = {0.f,0.f,0.f,0.f};
      f32x4 anh = {0.f,0.f,0.f,0.f};
      f32x4 ani = {0.f,0.f,0.f,0.f};
      #pragma unroll
      for (int kt = 0; kt < 12; kt++){
        f16x8 a  = *(const f16x8*)&Acat[nl*392 + kt*32 + kh];
        f16x8 br = *(const f16x8*)&Bb[(size_t)kt*512 + l*8];
        f16x8 bz = *(const f16x8*)&Bb[(size_t)(12+kt)*512 + l*8];
        ar = __builtin_amdgcn_mfma_f32_16x16x32_f16(a, br, ar, 0, 0, 0);
        az = __builtin_amdgcn_mfma_f32_16x16x32_f16(a, bz, az, 0, 0, 0);
        if (kt < 8){
          f16x8 bn = *(const f16x8*)&Bb[(size_t)(24+kt)*512 + l*8];
          anh = __builtin_amdgcn_mfma_f32_16x16x32_f16(a, bn, anh, 0, 0, 0);
        } else {
          f16x8 bn = *(const f16x8*)&Bb[(size_t)(32+kt-8)*512 + l*8];
          ani = __builtin_amdgcn_mfma_f32_16x16x32_f16(a, bn, ani, 0, 0, 0);
        }
      }
      int j = jb*16 + nl;
      float br_ = b_ih[j]       + b_hh[j];
      float bz_ = b_ih[256+j]   + b_hh[256+j];
      float bni = b_ih[512+j];
      float bnh = b_hh[512+j];
      #pragma unroll
      for (int q = 0; q < 4; q++){
        int m = mq + q;
        float rg = sigm(ar[q] + br_);
        float zg = sigm(az[q] + bz_);
        float ng = tanhf(ani[q] + bni + rg*(anh[q] + bnh));
        float hold = sh[m*260 + j];
        float hn = (1.f-zg)*ng + zg*hold;
        sh[m*260 + j] = hn;
        out_hs[((size_t)(row0+m)*TT + t)*HHID + j] = hn;
      }
    }
    __syncthreads();
  }
}

// =====================================================================
// finalize: x_loss and classification head
// =====================================================================
__global__ __launch_bounds__(256) void final_kernel(
    const float* __restrict__ hs, const float* __restrict__ cls_W,
    const float* __restrict__ cls_b, const float* __restrict__ ws_num,
    const float* __restrict__ ws_den, float* __restrict__ out)
{
  int b = blockIdx.x*256 + threadIdx.x;
  if (b < BATCH){
    const float* hr = hs + ((size_t)b*TT + (TT-1))*HHID;
    float acc = cls_b[0];
    for (int j = 0; j < HHID; j++) acc += hr[j]*cls_W[j];
    out[OFF_YOUT + b] = acc;
    out[OFF_YSC  + b] = sigm(acc);
  }
  if (blockIdx.x == 0 && threadIdx.x == 0){
    float s = 0.f;
    for (int tt = 0; tt < TT; tt++) s += ws_num[tt]/(ws_den[tt] + 1e-5f);
    out[OFF_LOSS] = s;
  }
}

extern "C" void kernel_launch(void* const* d_in, const int* in_sizes, int n_in,
                              void* d_out, int out_size, void* d_ws, size_t ws_size,
                              hipStream_t stream)
{
  const float* x       = (const float*)d_in[0];
  const float* mask_   = (const float*)d_in[1];
  const float* deltas  = (const float*)d_in[2];
  const float* h0      = (const float*)d_in[4];
  const float* medians = (const float*)d_in[5];
  const float* W_dh    = (const float*)d_in[6];
  const float* b_dh    = (const float*)d_in[7];
  const float* W_dx    = (const float*)d_in[8];
  const float* b_dx    = (const float*)d_in[9];
  const float* hist_W  = (const float*)d_in[10];
  const float* hist_b  = (const float*)d_in[11];
  const float* feat_W  = (const float*)d_in[12];
  const float* feat_b  = (const float*)d_in[13];
  const float* wcomb_W = (const float*)d_in[14];
  const float* wcomb_b = (const float*)d_in[15];
  const float* wobs_W  = (const float*)d_in[16];
  const float* wobs_b  = (const float*)d_in[17];
  const float* W_ih    = (const float*)d_in[18];
  const float* W_hh    = (const float*)d_in[19];
  const float* b_ih    = (const float*)d_in[20];
  const float* b_hh    = (const float*)d_in[21];
  const float* cls_W   = (const float*)d_in[22];
  const float* cls_b   = (const float*)d_in[23];

  float* out    = (float*)d_out;
  float* ws_num = (float*)d_ws;              // 48 floats
  float* ws_den = ws_num + TT;               // 48 floats
  f16*   wbase  = (f16*)((char*)d_ws + 512); // f16 weight blocks

  hipMemsetAsync(d_ws, 0, 512, stream);

  conv_kernel<<<166, 256, 0, stream>>>(W_dh, hist_W, feat_W, wcomb_W,
                                       W_ih, W_hh, wbase);

  decay_kernel<<<BATCH*TT/16, 256, 0, stream>>>(deltas, medians, wobs_W, wobs_b,
                                                out + OFF_DEC);

  seq_kernel<<<NWG, NTHR, 0, stream>>>(x, mask_, deltas, h0,
      b_dh, W_dx, b_dx, hist_b, feat_b, wcomb_b, b_ih, b_hh, wbase,
      out /*x_imp*/, out + OFF_HS, ws_num, ws_den);

  final_kernel<<<BATCH/256, 256, 0, stream>>>(out + OFF_HS, cls_W, cls_b,
                                              ws_num, ws_den, out);
}